// Round 13
// baseline (388.310 us; speedup 1.0000x reference)
//
#include <hip/hip_runtime.h>
#include <hip/hip_bf16.h>
#include <hip/hip_cooperative_groups.h>

namespace cg = cooperative_groups;

#define N_NODES 50000
#define N_EDGES 800000
#define DIM 256      // input feature dim = K
#define QKDIM 256    // packed q|k per node (fp8: 256 B/row)
#define NB_T  391    // d0 target buckets: d0 >> 7 (128 nodes per bucket)
#define ITEMS (2 * N_EDGES)
// --- R12 fallback slotted-binning params (proven) ---
#define NBLK_P 391
#define SLOT  32
#define CAPB  (NBLK_P * SLOT)   // 12512 slots per bucket
#define IPB   4096
// --- mega-kernel slotted-binning params (192 virtual blocks) ---
#define NVB   192
#define SLOTV 64                // lambda 21.3 -> +9.2 sigma, P(ovf) ~ 1e-8
#define IPBV  8334              // 192 * 8334 >= 1.6M
#define CAPBV (NVB * SLOTV)     // 12288 slots per bucket
#define PROJ_TILES 782          // ceil(50000/64)
// pre = (0.5/H) * sum_A (q_s k_d + q_d k_s) = (full rotated 256-dot)/16

typedef __bf16 bfrag  __attribute__((ext_vector_type(8)));
typedef __bf16 bf4    __attribute__((ext_vector_type(4)));
typedef float  ffrag  __attribute__((ext_vector_type(4)));
typedef float  f2     __attribute__((ext_vector_type(2)));
typedef float  f4v    __attribute__((ext_vector_type(4)));

#define EP_PITCH 272   // epilogue LDS byte pitch (256+16)

// ===================== device helpers (mega phases) =========================

// proj one 64-node tile; W converted fp32->bf16 on the fly (R11-proven).
__device__ __forceinline__ void proj_tile_dev(
    int tile, const float* __restrict__ x,
    const float* __restrict__ Wq, const float* __restrict__ Wk,
    const float* __restrict__ bq, const float* __restrict__ bk,
    unsigned char* __restrict__ qk8, unsigned char* smem)
{
    __bf16* As = (__bf16*)smem;          // 32 KB fragment-order
    const int tid  = threadIdx.x;
    const int wv   = tid >> 6;
    const int lane = tid & 63;
    const int m    = lane & 15;
    const int q    = lane >> 4;
    const int mbase = tile * 64;

    {   // stage A (64 rows x 256 k fp32 -> bf16 frags)
        const int srow = tid >> 2;
        const int c4   = tid & 3;
        int grow = mbase + srow;
        grow = grow < N_NODES ? grow : N_NODES - 1;
        const float* xp = x + (size_t)grow * DIM;
        const int mt_ = srow >> 4, m_ = srow & 15;
        #pragma unroll
        for (int i = 0; i < 16; ++i) {
            const int k = c4 * 4 + 16 * i;
            const f4v v = __builtin_nontemporal_load((const f4v*)(xp + k));
            bf4 o;
            o[0] = (__bf16)v[0]; o[1] = (__bf16)v[1];
            o[2] = (__bf16)v[2]; o[3] = (__bf16)v[3];
            const int seg = (k >> 5) * 4 + mt_;
            const int ln  = ((k >> 3) & 3) * 16 + m_;
            *(bf4*)(As + seg * 512 + ln * 8 + (k & 7)) = o;
        }
    }
    __syncthreads();

    ffrag acc[4][4] = {};

    #pragma unroll
    for (int h = 0; h < 2; ++h) {
        bfrag b[4][4];
        #pragma unroll
        for (int sp = 0; sp < 4; ++sp)
            #pragma unroll
            for (int nt = 0; nt < 4; ++nt) {
                const int col = wv * 64 + nt * 16 + m;
                const float* wrow = (col < 128)
                    ? (Wq + (size_t)col * DIM)
                    : (Wk + (size_t)(col - 128) * DIM);
                const int k0 = 32 * (4 * h + sp) + 8 * q;
                const float4 f0 = *(const float4*)(wrow + k0);
                const float4 f1 = *(const float4*)(wrow + k0 + 4);
                bfrag o;
                o[0] = (__bf16)f0.x; o[1] = (__bf16)f0.y;
                o[2] = (__bf16)f0.z; o[3] = (__bf16)f0.w;
                o[4] = (__bf16)f1.x; o[5] = (__bf16)f1.y;
                o[6] = (__bf16)f1.z; o[7] = (__bf16)f1.w;
                b[sp][nt] = o;
            }
        #pragma unroll
        for (int sp = 0; sp < 4; ++sp) {
            bfrag a[4];
            #pragma unroll
            for (int mt = 0; mt < 4; ++mt)
                a[mt] = *(const bfrag*)(As + ((4 * h + sp) * 4 + mt) * 512 + lane * 8);
            #pragma unroll
            for (int mt = 0; mt < 4; ++mt)
                #pragma unroll
                for (int nt = 0; nt < 4; ++nt)
                    acc[mt][nt] = __builtin_amdgcn_mfma_f32_16x16x32_bf16(
                                      a[mt], b[sp][nt], acc[mt][nt], 0, 0, 0);
        }
    }

    __syncthreads();
    unsigned char* ep = (unsigned char*)As;   // [64][EP_PITCH] bytes
    #pragma unroll
    for (int nt = 0; nt < 4; ++nt) {
        const int col  = wv * 64 + nt * 16 + m;
        const float bias = (col < 128) ? bq[col] : bk[col - 128];
        #pragma unroll
        for (int mt = 0; mt < 4; ++mt) {
            #pragma unroll
            for (int r = 0; r < 4; ++r) {
                const int rl = mt * 16 + q * 4 + r;
                const float v = acc[mt][nt][r] + bias;
                const int pk = __builtin_amdgcn_cvt_pk_fp8_f32(v, v, 0, false);
                ep[rl * EP_PITCH + col] = (unsigned char)(pk & 0xFF);
            }
        }
    }
    __syncthreads();
    {
        const int rl = tid >> 2;
        const int ch = tid & 3;
        const int grow = mbase + rl;
        if (grow < N_NODES) {
            const uint4* s4 = (const uint4*)(ep + rl * EP_PITCH + ch * 64);
            const uint4 t0 = s4[0], t1 = s4[1], t2 = s4[2], t3 = s4[3];
            uint4* g = (uint4*)(qk8 + (size_t)grow * QKDIM + ch * 64);
            g[0] = t0; g[1] = t1; g[2] = t2; g[3] = t3;
        }
    }
    __syncthreads();   // smem reuse safety before next tile
}

// slotted d0 binning for one virtual block (two read passes, LDS atomics only)
__device__ __forceinline__ void bin_virtual_dev(
    int vb, const int* __restrict__ d0, unsigned int* __restrict__ rec,
    unsigned char* __restrict__ cnts, unsigned char* smem)
{
    int* lcnt = (int*)smem;
    const int tid = threadIdx.x;
    for (int b = tid; b < NB_T; b += 256) lcnt[b] = 0;
    __syncthreads();
    const int base = vb * IPBV;
    const int lim = (base + IPBV < ITEMS) ? base + IPBV : ITEMS;
    for (int i = base + tid; i < lim; i += 256)
        atomicAdd(&lcnt[d0[i] >> 7], 1);
    __syncthreads();
    for (int b = tid; b < NB_T; b += 256) {
        const int c = lcnt[b];
        cnts[(size_t)vb * NB_T + b] = (unsigned char)(c < SLOTV ? c : SLOTV);
        lcnt[b] = 0;
    }
    __syncthreads();
    for (int i = base + tid; i < lim; i += 256) {
        const int t = d0[i];
        const int b = t >> 7;
        const int off = atomicAdd(&lcnt[b], 1);
        if (off < SLOTV)
            rec[(size_t)b * CAPBV + vb * SLOTV + off] =
                ((unsigned int)(t & 127) << 20) | (unsigned int)(i >> 1);
    }
    __syncthreads();
}

// ===================== mega cooperative kernel ==============================
__global__ __launch_bounds__(256, 4) void mega(
    const float* __restrict__ x,
    const float* __restrict__ Wq, const float* __restrict__ Wk,
    const float* __restrict__ bq, const float* __restrict__ bk,
    const int* __restrict__ edge_index, const int* __restrict__ d0,
    float* __restrict__ out, unsigned char* __restrict__ qk8,
    unsigned int* __restrict__ rec, unsigned char* __restrict__ cnts)
{
    cg::grid_group grid = cg::this_grid();
    __shared__ unsigned char smem[32768];
    const int G = gridDim.x;
    const int bid = blockIdx.x;
    const int tid = threadIdx.x;
    const int nproj = G - NVB;

    // ---- phase 1: proj tiles (blocks [0,nproj)) || d0 binning (last NVB) ---
    if (bid < nproj) {
        for (int tile = bid; tile < PROJ_TILES; tile += nproj)
            proj_tile_dev(tile, x, Wq, Wk, bq, bk, qk8, smem);
    } else {
        bin_virtual_dev(bid - nproj, d0, rec, cnts, smem);
    }
    grid.sync();

    // ---- phase 2: edge scoring (R9 known-good body), grid-strided ----------
    {
        const int lane = tid & 63;
        const int g = lane >> 2;
        const int j = lane & 3;
        const int gw = (bid << 2) + (tid >> 6);
        const int nwv = G << 2;
        for (int wu = gw; wu < N_EDGES / 16; wu += nwv) {
            const int e = wu * 16 + g;
            const int src = __builtin_nontemporal_load(edge_index + e);
            const int dst = __builtin_nontemporal_load(edge_index + N_EDGES + e);

            const uint4* rs = (const uint4*)(qk8 + (size_t)src * QKDIM);
            const uint4* rd = (const uint4*)(qk8 + (size_t)dst * QKDIM);

            uint4 a[4], b[4];
            #pragma unroll
            for (int i = 0; i < 4; ++i) a[i] = rs[4 * i + j];
            #pragma unroll
            for (int i = 0; i < 4; ++i) b[i] = rd[4 * ((i + 2) & 3) + j];

            f2 acc = {0.f, 0.f};
            #pragma unroll
            for (int i = 0; i < 4; ++i) {
                const unsigned int* ua = (const unsigned int*)&a[i];
                const unsigned int* ub = (const unsigned int*)&b[i];
                #pragma unroll
                for (int t = 0; t < 4; ++t) {
                    const f2 x0 = __builtin_amdgcn_cvt_pk_f32_fp8(ua[t], false);
                    const f2 y0 = __builtin_amdgcn_cvt_pk_f32_fp8(ub[t], false);
                    const f2 x1 = __builtin_amdgcn_cvt_pk_f32_fp8(ua[t], true);
                    const f2 y1 = __builtin_amdgcn_cvt_pk_f32_fp8(ub[t], true);
                    acc += x0 * y0;
                    acc += x1 * y1;
                }
            }
            float p = acc[0] + acc[1];
            p += __shfl_xor(p, 1, 64);
            p += __shfl_xor(p, 2, 64);
            if (j == 0)
                out[N_NODES + e] = __expf(p * 0.0625f);
        }
    }
    grid.sync();

    // ---- phase 3: scatter, grid-strided buckets ----------------------------
    {
        float (*acc)[128] = (float (*)[128])smem;          // 4 waves x 128
        unsigned char* lc = smem + 2048;                   // NVB bytes
        const int wid = tid >> 6;
        for (int b = bid; b < NB_T; b += G) {
            for (int i = tid; i < 512; i += 256) ((float*)acc)[i] = 0.f;
            if (tid < NVB) lc[tid] = cnts[(size_t)tid * NB_T + b];
            __syncthreads();

            const unsigned int* rb = rec + (size_t)b * CAPBV;
            for (int s = tid; s < CAPBV; s += 256) {
                const int vb = s >> 6;                     // SLOTV = 64
                const int off = s & (SLOTV - 1);
                if (off < (int)lc[vb]) {
                    const unsigned int r = rb[s];
                    const float v = out[N_NODES + (r & 0xFFFFF)];
                    atomicAdd(&acc[wid][r >> 20], v);
                }
            }
            __syncthreads();
            if (tid < 128) {
                float s = 0.f;
                #pragma unroll
                for (int w = 0; w < 4; ++w) s += acc[w][tid];
                const int n = b * 128 + tid;
                if (n < N_NODES) out[n] = s;
            }
            __syncthreads();
        }
    }
}

// ===================== R12 fallback kernels (proven) ========================

__global__ __launch_bounds__(512) void prep_bin(
    const float* __restrict__ Wq, const float* __restrict__ Wk,
    __bf16* __restrict__ Wb,
    const int* __restrict__ d0, unsigned int* __restrict__ rec,
    unsigned char* __restrict__ cnts, int do_bin)
{
    __shared__ int lcnt[NB_T];
    const int tid = threadIdx.x;
    const int gtid = blockIdx.x * 512 + tid;

    const int i4 = gtid * 4;
    if (i4 < 65536) {
        const float* s = (i4 < 32768) ? (Wq + i4) : (Wk + (i4 - 32768));
        const float4 v = *(const float4*)s;
        bf4 o;
        o[0] = (__bf16)v.x; o[1] = (__bf16)v.y; o[2] = (__bf16)v.z; o[3] = (__bf16)v.w;
        *(bf4*)(Wb + i4) = o;
    }
    if (!do_bin) return;

    for (int b = tid; b < NB_T; b += 512) lcnt[b] = 0;
    __syncthreads();
    const int base = blockIdx.x * IPB;
    int tg[8];
    #pragma unroll
    for (int r = 0; r < 8; ++r) {
        const int i = base + r * 512 + tid;
        tg[r] = (i < ITEMS) ? d0[i] : -1;
        if (tg[r] >= 0) atomicAdd(&lcnt[tg[r] >> 7], 1);
    }
    __syncthreads();
    for (int b = tid; b < NB_T; b += 512) {
        const int c = lcnt[b];
        cnts[(size_t)blockIdx.x * NB_T + b] = (unsigned char)(c < SLOT ? c : SLOT);
        lcnt[b] = 0;
    }
    __syncthreads();
    #pragma unroll
    for (int r = 0; r < 8; ++r) {
        if (tg[r] >= 0) {
            const int i = base + r * 512 + tid;
            const int b = tg[r] >> 7;
            const int off = atomicAdd(&lcnt[b], 1);
            if (off < SLOT)
                rec[(size_t)b * CAPB + blockIdx.x * SLOT + off] =
                    ((unsigned int)(tg[r] & 127) << 20) | (unsigned int)(i >> 1);
        }
    }
}

__global__ __launch_bounds__(256) void proj_mfma(
    const float* __restrict__ x,
    const __bf16* __restrict__ Wb,
    const float* __restrict__ bq, const float* __restrict__ bk,
    unsigned char* __restrict__ qk8)
{
    __shared__ __bf16 As[64 * 256];

    const int tid  = threadIdx.x;
    const int wv   = tid >> 6;
    const int lane = tid & 63;
    const int m    = lane & 15;
    const int q    = lane >> 4;
    const int mbase = blockIdx.x * 64;

    {
        const int srow = tid >> 2;
        const int c4   = tid & 3;
        int grow = mbase + srow;
        grow = grow < N_NODES ? grow : N_NODES - 1;
        const float* xp = x + (size_t)grow * DIM;
        const int mt_ = srow >> 4, m_ = srow & 15;
        #pragma unroll
        for (int i = 0; i < 16; ++i) {
            const int k = c4 * 4 + 16 * i;
            const f4v v = __builtin_nontemporal_load((const f4v*)(xp + k));
            bf4 o;
            o[0] = (__bf16)v[0]; o[1] = (__bf16)v[1];
            o[2] = (__bf16)v[2]; o[3] = (__bf16)v[3];
            const int seg = (k >> 5) * 4 + mt_;
            const int ln  = ((k >> 3) & 3) * 16 + m_;
            *(bf4*)(As + seg * 512 + ln * 8 + (k & 7)) = o;
        }
    }
    __syncthreads();

    ffrag acc[4][4] = {};

    #pragma unroll
    for (int h = 0; h < 2; ++h) {
        bfrag b[4][4];
        #pragma unroll
        for (int sp = 0; sp < 4; ++sp)
            #pragma unroll
            for (int nt = 0; nt < 4; ++nt) {
                const int col = wv * 64 + nt * 16 + m;
                b[sp][nt] = *(const bfrag*)(Wb + (size_t)col * DIM
                                            + 32 * (4 * h + sp) + 8 * q);
            }
        #pragma unroll
        for (int sp = 0; sp < 4; ++sp) {
            bfrag a[4];
            #pragma unroll
            for (int mt = 0; mt < 4; ++mt)
                a[mt] = *(const bfrag*)(As + ((4 * h + sp) * 4 + mt) * 512 + lane * 8);
            #pragma unroll
            for (int mt = 0; mt < 4; ++mt)
                #pragma unroll
                for (int nt = 0; nt < 4; ++nt)
                    acc[mt][nt] = __builtin_amdgcn_mfma_f32_16x16x32_bf16(
                                      a[mt], b[sp][nt], acc[mt][nt], 0, 0, 0);
        }
    }

    __syncthreads();
    unsigned char* ep = (unsigned char*)As;
    #pragma unroll
    for (int nt = 0; nt < 4; ++nt) {
        const int col  = wv * 64 + nt * 16 + m;
        const float bias = (col < 128) ? bq[col] : bk[col - 128];
        #pragma unroll
        for (int mt = 0; mt < 4; ++mt) {
            #pragma unroll
            for (int r = 0; r < 4; ++r) {
                const int rl = mt * 16 + q * 4 + r;
                const float v = acc[mt][nt][r] + bias;
                const int pk = __builtin_amdgcn_cvt_pk_fp8_f32(v, v, 0, false);
                ep[rl * EP_PITCH + col] = (unsigned char)(pk & 0xFF);
            }
        }
    }
    __syncthreads();
    {
        const int rl = tid >> 2;
        const int ch = tid & 3;
        const int grow = mbase + rl;
        if (grow < N_NODES) {
            const uint4* s4 = (const uint4*)(ep + rl * EP_PITCH + ch * 64);
            const uint4 t0 = s4[0], t1 = s4[1], t2 = s4[2], t3 = s4[3];
            uint4* g = (uint4*)(qk8 + (size_t)grow * QKDIM + ch * 64);
            g[0] = t0; g[1] = t1; g[2] = t2; g[3] = t3;
        }
    }
}

__global__ __launch_bounds__(256) void edge_compute(
    const unsigned char* __restrict__ qk8,
    const int* __restrict__ edge_index,
    float* __restrict__ out)
{
    const int wave = (blockIdx.x * blockDim.x + threadIdx.x) >> 6;
    const int lane = threadIdx.x & 63;
    const int g = lane >> 2;
    const int j = lane & 3;
    const int e = wave * 16 + g;

    const int src = __builtin_nontemporal_load(edge_index + e);
    const int dst = __builtin_nontemporal_load(edge_index + N_EDGES + e);

    const uint4* rs = (const uint4*)(qk8 + (size_t)src * QKDIM);
    const uint4* rd = (const uint4*)(qk8 + (size_t)dst * QKDIM);

    uint4 a[4], b[4];
    #pragma unroll
    for (int i = 0; i < 4; ++i) a[i] = rs[4 * i + j];
    #pragma unroll
    for (int i = 0; i < 4; ++i) b[i] = rd[4 * ((i + 2) & 3) + j];

    f2 acc = {0.f, 0.f};
    #pragma unroll
    for (int i = 0; i < 4; ++i) {
        const unsigned int* ua = (const unsigned int*)&a[i];
        const unsigned int* ub = (const unsigned int*)&b[i];
        #pragma unroll
        for (int t = 0; t < 4; ++t) {
            const f2 x0 = __builtin_amdgcn_cvt_pk_f32_fp8(ua[t], false);
            const f2 y0 = __builtin_amdgcn_cvt_pk_f32_fp8(ub[t], false);
            const f2 x1 = __builtin_amdgcn_cvt_pk_f32_fp8(ua[t], true);
            const f2 y1 = __builtin_amdgcn_cvt_pk_f32_fp8(ub[t], true);
            acc += x0 * y0;
            acc += x1 * y1;
        }
    }
    float p = acc[0] + acc[1];
    p += __shfl_xor(p, 1, 64);
    p += __shfl_xor(p, 2, 64);

    if (j == 0)
        out[N_NODES + e] = __expf(p * 0.0625f);
}

__global__ __launch_bounds__(1024) void phase_scatter(
    const unsigned int* __restrict__ rec, const unsigned char* __restrict__ cnts,
    float* __restrict__ out)
{
    __shared__ float acc[16][128];
    __shared__ unsigned char lc[NBLK_P];
    const int b = blockIdx.x;
    const int tid = threadIdx.x;
    const int wid = tid >> 6;
    for (int i = tid; i < 16 * 128; i += 1024) ((float*)acc)[i] = 0.f;
    if (tid < NBLK_P) lc[tid] = cnts[(size_t)tid * NB_T + b];
    __syncthreads();

    const unsigned int* rb = rec + (size_t)b * CAPB;
    for (int s = tid; s < CAPB; s += 1024) {
        const int blk = s >> 5;
        const int off = s & (SLOT - 1);
        if (off < (int)lc[blk]) {
            const unsigned int r = rb[s];
            const float v = out[N_NODES + (r & 0xFFFFF)];
            atomicAdd(&acc[wid][r >> 20], v);
        }
    }
    __syncthreads();

    if (tid < 128) {
        float s = 0.f;
        #pragma unroll
        for (int w = 0; w < 16; ++w) s += acc[w][tid];
        const int n = b * 128 + tid;
        if (n < N_NODES) out[n] = s;
    }
}

// ===================== launcher =============================================

extern "C" void kernel_launch(void* const* d_in, const int* in_sizes, int n_in,
                              void* d_out, int out_size, void* d_ws, size_t ws_size,
                              hipStream_t stream) {
    const float* x  = (const float*)d_in[0];
    const float* Wq = (const float*)d_in[1];
    const float* bq = (const float*)d_in[2];
    const float* Wk = (const float*)d_in[3];
    const float* bk = (const float*)d_in[4];
    const int* edge_index = (const int*)d_in[5];
    const int* d0 = (const int*)d_in[6] + 2 * N_EDGES;  // row 1 of d0_index
    float* out = (float*)d_out;

    char* w = (char*)d_ws;
    unsigned char* qk8 = (unsigned char*)w;  w += (size_t)N_NODES * QKDIM;   // 12.8 MB
    __bf16* Wb = (__bf16*)w;                 w += 131072;                    // 128 KB
    unsigned int* rec = (unsigned int*)w;    w += (size_t)NB_T * CAPB * 4;   // 19.6 MB (covers mega's 19.2)
    unsigned char* cnts = (unsigned char*)w; w += (size_t)NBLK_P * NB_T;     // 150 KB

    const size_t need = (size_t)(w - (char*)d_ws);
    const int ws_ok = (ws_size >= need) ? 1 : 0;

    // one-time cooperative capability + occupancy probe
    static int s_G = -2;
    if (s_G == -2) {
        int coop = 0, nsm = 0, occ = 0;
        hipDeviceGetAttribute(&coop, hipDeviceAttributeCooperativeLaunch, 0);
        hipDeviceGetAttribute(&nsm, hipDeviceAttributeMultiprocessorCount, 0);
        hipOccupancyMaxActiveBlocksPerMultiprocessor(&occ, mega, 256, 0);
        int g = (coop && occ > 0 && nsm > 0) ? occ * nsm : -1;
        if (g < NVB + 256) g = -1;   // need proj blocks + NVB bin blocks
        if (g > 2048) g = 2048;
        s_G = g;
    }

    if (ws_ok && s_G > 0) {
        void* args[] = { (void*)&x, (void*)&Wq, (void*)&Wk, (void*)&bq, (void*)&bk,
                         (void*)&edge_index, (void*)&d0, (void*)&out,
                         (void*)&qk8, (void*)&rec, (void*)&cnts };
        hipLaunchCooperativeKernel((const void*)mega, dim3(s_G), dim3(256),
                                   args, 0, stream);
    } else if (ws_ok) {
        // proven R12 4-dispatch path
        prep_bin<<<NBLK_P, 512, 0, stream>>>(Wq, Wk, Wb, d0, rec, cnts, 1);
        proj_mfma<<<(N_NODES + 63) / 64, 256, 0, stream>>>(x, Wb, bq, bk, qk8);
        edge_compute<<<N_EDGES / 64, 256, 0, stream>>>(qk8, edge_index, out);
        phase_scatter<<<NB_T, 1024, 0, stream>>>(rec, cnts, out);
    } else {
        // minimal fallback: R12 path without binning region is not possible;
        // reuse prep (W only) + proj + edge with direct atomics into out.
        hipMemsetAsync(out, 0, N_NODES * sizeof(float), stream);
        prep_bin<<<NBLK_P, 512, 0, stream>>>(Wq, Wk, Wb, d0, rec, cnts, 0);
        proj_mfma<<<(N_NODES + 63) / 64, 256, 0, stream>>>(x, Wb, bq, bk, qk8);
        edge_compute<<<N_EDGES / 64, 256, 0, stream>>>(qk8, edge_index, out);
        phase_scatter<<<NB_T, 1024, 0, stream>>>(rec, cnts, out);
    }
}

// Round 14
// 195.189 us; speedup vs baseline: 1.9894x; 1.9894x over previous
//
#include <hip/hip_runtime.h>
#include <hip/hip_bf16.h>
#include <hip/hip_cooperative_groups.h>

namespace cg = cooperative_groups;

#define N_NODES 50000
#define N_EDGES 800000
#define DIM 256      // input feature dim = K
#define QKDIM 256    // packed q|k per node (fp8: 256 B/row)
#define NB_T  391    // d0 target buckets: d0 >> 7 (128 nodes per bucket)
#define ITEMS (2 * N_EDGES)
// --- R12 fallback slotted-binning params (proven) ---
#define NBLK_P 391
#define SLOT  32
#define CAPB  (NBLK_P * SLOT)   // 12512 slots per bucket
#define IPB   4096
// --- mega-kernel slotted-binning params (192 virtual blocks) ---
#define NVB   192
#define SLOTV 64                // lambda 21.3 -> +9.2 sigma, P(ovf) ~ 1e-8
#define IPBV  8334              // 192 * 8334 >= 1.6M
#define CAPBV (NVB * SLOTV)     // 12288 slots per bucket
#define PROJ_TILES 782          // ceil(50000/64)
// pre = (0.5/H) * sum_A (q_s k_d + q_d k_s) = (full rotated 256-dot)/16

typedef __bf16 bfrag  __attribute__((ext_vector_type(8)));
typedef __bf16 bf4    __attribute__((ext_vector_type(4)));
typedef float  ffrag  __attribute__((ext_vector_type(4)));
typedef float  f2     __attribute__((ext_vector_type(2)));
typedef float  f4v    __attribute__((ext_vector_type(4)));

#define EP_PITCH 272   // epilogue LDS byte pitch (256+16)

// ===================== device helpers (mega phases) =========================

// proj one 64-node tile; W converted fp32->bf16 on the fly (R11-proven, 124 VGPR).
__device__ __forceinline__ void proj_tile_dev(
    int tile, const float* __restrict__ x,
    const float* __restrict__ Wq, const float* __restrict__ Wk,
    const float* __restrict__ bq, const float* __restrict__ bk,
    unsigned char* __restrict__ qk8, unsigned char* smem)
{
    __bf16* As = (__bf16*)smem;          // 32 KB fragment-order
    const int tid  = threadIdx.x;
    const int wv   = tid >> 6;
    const int lane = tid & 63;
    const int m    = lane & 15;
    const int q    = lane >> 4;
    const int mbase = tile * 64;

    {   // stage A (64 rows x 256 k fp32 -> bf16 frags)
        const int srow = tid >> 2;
        const int c4   = tid & 3;
        int grow = mbase + srow;
        grow = grow < N_NODES ? grow : N_NODES - 1;
        const float* xp = x + (size_t)grow * DIM;
        const int mt_ = srow >> 4, m_ = srow & 15;
        #pragma unroll
        for (int i = 0; i < 16; ++i) {
            const int k = c4 * 4 + 16 * i;
            const f4v v = __builtin_nontemporal_load((const f4v*)(xp + k));
            bf4 o;
            o[0] = (__bf16)v[0]; o[1] = (__bf16)v[1];
            o[2] = (__bf16)v[2]; o[3] = (__bf16)v[3];
            const int seg = (k >> 5) * 4 + mt_;
            const int ln  = ((k >> 3) & 3) * 16 + m_;
            *(bf4*)(As + seg * 512 + ln * 8 + (k & 7)) = o;
        }
    }
    __syncthreads();

    ffrag acc[4][4] = {};

    #pragma unroll
    for (int h = 0; h < 2; ++h) {
        bfrag b[4][4];
        #pragma unroll
        for (int sp = 0; sp < 4; ++sp)
            #pragma unroll
            for (int nt = 0; nt < 4; ++nt) {
                const int col = wv * 64 + nt * 16 + m;
                const float* wrow = (col < 128)
                    ? (Wq + (size_t)col * DIM)
                    : (Wk + (size_t)(col - 128) * DIM);
                const int k0 = 32 * (4 * h + sp) + 8 * q;
                const float4 f0 = *(const float4*)(wrow + k0);
                const float4 f1 = *(const float4*)(wrow + k0 + 4);
                bfrag o;
                o[0] = (__bf16)f0.x; o[1] = (__bf16)f0.y;
                o[2] = (__bf16)f0.z; o[3] = (__bf16)f0.w;
                o[4] = (__bf16)f1.x; o[5] = (__bf16)f1.y;
                o[6] = (__bf16)f1.z; o[7] = (__bf16)f1.w;
                b[sp][nt] = o;
            }
        #pragma unroll
        for (int sp = 0; sp < 4; ++sp) {
            bfrag a[4];
            #pragma unroll
            for (int mt = 0; mt < 4; ++mt)
                a[mt] = *(const bfrag*)(As + ((4 * h + sp) * 4 + mt) * 512 + lane * 8);
            #pragma unroll
            for (int mt = 0; mt < 4; ++mt)
                #pragma unroll
                for (int nt = 0; nt < 4; ++nt)
                    acc[mt][nt] = __builtin_amdgcn_mfma_f32_16x16x32_bf16(
                                      a[mt], b[sp][nt], acc[mt][nt], 0, 0, 0);
        }
    }

    __syncthreads();
    unsigned char* ep = (unsigned char*)As;   // [64][EP_PITCH] bytes
    #pragma unroll
    for (int nt = 0; nt < 4; ++nt) {
        const int col  = wv * 64 + nt * 16 + m;
        const float bias = (col < 128) ? bq[col] : bk[col - 128];
        #pragma unroll
        for (int mt = 0; mt < 4; ++mt) {
            #pragma unroll
            for (int r = 0; r < 4; ++r) {
                const int rl = mt * 16 + q * 4 + r;
                const float v = acc[mt][nt][r] + bias;
                const int pk = __builtin_amdgcn_cvt_pk_fp8_f32(v, v, 0, false);
                ep[rl * EP_PITCH + col] = (unsigned char)(pk & 0xFF);
            }
        }
    }
    __syncthreads();
    {
        const int rl = tid >> 2;
        const int ch = tid & 3;
        const int grow = mbase + rl;
        if (grow < N_NODES) {
            const uint4* s4 = (const uint4*)(ep + rl * EP_PITCH + ch * 64);
            const uint4 t0 = s4[0], t1 = s4[1], t2 = s4[2], t3 = s4[3];
            uint4* g = (uint4*)(qk8 + (size_t)grow * QKDIM + ch * 64);
            g[0] = t0; g[1] = t1; g[2] = t2; g[3] = t3;
        }
    }
    __syncthreads();   // smem reuse safety before next tile
}

// slotted d0 binning for one virtual block (two read passes, LDS atomics only)
__device__ __forceinline__ void bin_virtual_dev(
    int vb, const int* __restrict__ d0, unsigned int* __restrict__ rec,
    unsigned char* __restrict__ cnts, unsigned char* smem)
{
    int* lcnt = (int*)smem;
    const int tid = threadIdx.x;
    for (int b = tid; b < NB_T; b += 256) lcnt[b] = 0;
    __syncthreads();
    const int base = vb * IPBV;
    const int lim = (base + IPBV < ITEMS) ? base + IPBV : ITEMS;
    for (int i = base + tid; i < lim; i += 256)
        atomicAdd(&lcnt[d0[i] >> 7], 1);
    __syncthreads();
    for (int b = tid; b < NB_T; b += 256) {
        const int c = lcnt[b];
        cnts[(size_t)vb * NB_T + b] = (unsigned char)(c < SLOTV ? c : SLOTV);
        lcnt[b] = 0;
    }
    __syncthreads();
    for (int i = base + tid; i < lim; i += 256) {
        const int t = d0[i];
        const int b = t >> 7;
        const int off = atomicAdd(&lcnt[b], 1);
        if (off < SLOTV)
            rec[(size_t)b * CAPBV + vb * SLOTV + off] =
                ((unsigned int)(t & 127) << 20) | (unsigned int)(i >> 1);
    }
    __syncthreads();
}

// ===================== mega cooperative kernel ==============================
// NOTE: __launch_bounds__(256) ONLY — R13's (256,4) capped VGPR at 64 and the
// proj phase (needs ~124) spilled to scratch: WRITE_SIZE 133 MB, 442 us.
__global__ __launch_bounds__(256) void mega(
    const float* __restrict__ x,
    const float* __restrict__ Wq, const float* __restrict__ Wk,
    const float* __restrict__ bq, const float* __restrict__ bk,
    const int* __restrict__ edge_index, const int* __restrict__ d0,
    float* __restrict__ out, unsigned char* __restrict__ qk8,
    unsigned int* __restrict__ rec, unsigned char* __restrict__ cnts)
{
    cg::grid_group grid = cg::this_grid();
    __shared__ unsigned char smem[32768];
    const int G = gridDim.x;
    const int bid = blockIdx.x;
    const int tid = threadIdx.x;
    const int nproj = G - NVB;

    // ---- phase 1: proj tiles (blocks [0,nproj)) || d0 binning (last NVB) ---
    if (bid < nproj) {
        for (int tile = bid; tile < PROJ_TILES; tile += nproj)
            proj_tile_dev(tile, x, Wq, Wk, bq, bk, qk8, smem);
    } else {
        bin_virtual_dev(bid - nproj, d0, rec, cnts, smem);
    }
    grid.sync();

    // ---- phase 2: edge scoring (R9 known-good body), grid-strided ----------
    {
        const int lane = tid & 63;
        const int g = lane >> 2;
        const int j = lane & 3;
        const int gw = (bid << 2) + (tid >> 6);
        const int nwv = G << 2;
        for (int wu = gw; wu < N_EDGES / 16; wu += nwv) {
            const int e = wu * 16 + g;
            const int src = __builtin_nontemporal_load(edge_index + e);
            const int dst = __builtin_nontemporal_load(edge_index + N_EDGES + e);

            const uint4* rs = (const uint4*)(qk8 + (size_t)src * QKDIM);
            const uint4* rd = (const uint4*)(qk8 + (size_t)dst * QKDIM);

            uint4 a[4], b[4];
            #pragma unroll
            for (int i = 0; i < 4; ++i) a[i] = rs[4 * i + j];
            #pragma unroll
            for (int i = 0; i < 4; ++i) b[i] = rd[4 * ((i + 2) & 3) + j];

            f2 acc = {0.f, 0.f};
            #pragma unroll
            for (int i = 0; i < 4; ++i) {
                const unsigned int* ua = (const unsigned int*)&a[i];
                const unsigned int* ub = (const unsigned int*)&b[i];
                #pragma unroll
                for (int t = 0; t < 4; ++t) {
                    const f2 x0 = __builtin_amdgcn_cvt_pk_f32_fp8(ua[t], false);
                    const f2 y0 = __builtin_amdgcn_cvt_pk_f32_fp8(ub[t], false);
                    const f2 x1 = __builtin_amdgcn_cvt_pk_f32_fp8(ua[t], true);
                    const f2 y1 = __builtin_amdgcn_cvt_pk_f32_fp8(ub[t], true);
                    acc += x0 * y0;
                    acc += x1 * y1;
                }
            }
            float p = acc[0] + acc[1];
            p += __shfl_xor(p, 1, 64);
            p += __shfl_xor(p, 2, 64);
            if (j == 0)
                out[N_NODES + e] = __expf(p * 0.0625f);
        }
    }
    grid.sync();

    // ---- phase 3: scatter, grid-strided buckets ----------------------------
    {
        float (*acc)[128] = (float (*)[128])smem;          // 4 waves x 128
        unsigned char* lc = smem + 2048;                   // NVB bytes
        const int wid = tid >> 6;
        for (int b = bid; b < NB_T; b += G) {
            for (int i = tid; i < 512; i += 256) ((float*)acc)[i] = 0.f;
            if (tid < NVB) lc[tid] = cnts[(size_t)tid * NB_T + b];
            __syncthreads();

            const unsigned int* rb = rec + (size_t)b * CAPBV;
            for (int s = tid; s < CAPBV; s += 256) {
                const int vb = s >> 6;                     // SLOTV = 64
                const int off = s & (SLOTV - 1);
                if (off < (int)lc[vb]) {
                    const unsigned int r = rb[s];
                    const float v = out[N_NODES + (r & 0xFFFFF)];
                    atomicAdd(&acc[wid][r >> 20], v);
                }
            }
            __syncthreads();
            if (tid < 128) {
                float s = 0.f;
                #pragma unroll
                for (int w = 0; w < 4; ++w) s += acc[w][tid];
                const int n = b * 128 + tid;
                if (n < N_NODES) out[n] = s;
            }
            __syncthreads();
        }
    }
}

// ===================== R12 fallback kernels (proven) ========================

__global__ __launch_bounds__(512) void prep_bin(
    const float* __restrict__ Wq, const float* __restrict__ Wk,
    __bf16* __restrict__ Wb,
    const int* __restrict__ d0, unsigned int* __restrict__ rec,
    unsigned char* __restrict__ cnts, int do_bin)
{
    __shared__ int lcnt[NB_T];
    const int tid = threadIdx.x;
    const int gtid = blockIdx.x * 512 + tid;

    const int i4 = gtid * 4;
    if (i4 < 65536) {
        const float* s = (i4 < 32768) ? (Wq + i4) : (Wk + (i4 - 32768));
        const float4 v = *(const float4*)s;
        bf4 o;
        o[0] = (__bf16)v.x; o[1] = (__bf16)v.y; o[2] = (__bf16)v.z; o[3] = (__bf16)v.w;
        *(bf4*)(Wb + i4) = o;
    }
    if (!do_bin) return;

    for (int b = tid; b < NB_T; b += 512) lcnt[b] = 0;
    __syncthreads();
    const int base = blockIdx.x * IPB;
    int tg[8];
    #pragma unroll
    for (int r = 0; r < 8; ++r) {
        const int i = base + r * 512 + tid;
        tg[r] = (i < ITEMS) ? d0[i] : -1;
        if (tg[r] >= 0) atomicAdd(&lcnt[tg[r] >> 7], 1);
    }
    __syncthreads();
    for (int b = tid; b < NB_T; b += 512) {
        const int c = lcnt[b];
        cnts[(size_t)blockIdx.x * NB_T + b] = (unsigned char)(c < SLOT ? c : SLOT);
        lcnt[b] = 0;
    }
    __syncthreads();
    #pragma unroll
    for (int r = 0; r < 8; ++r) {
        if (tg[r] >= 0) {
            const int i = base + r * 512 + tid;
            const int b = tg[r] >> 7;
            const int off = atomicAdd(&lcnt[b], 1);
            if (off < SLOT)
                rec[(size_t)b * CAPB + blockIdx.x * SLOT + off] =
                    ((unsigned int)(tg[r] & 127) << 20) | (unsigned int)(i >> 1);
        }
    }
}

__global__ __launch_bounds__(256) void proj_mfma(
    const float* __restrict__ x,
    const __bf16* __restrict__ Wb,
    const float* __restrict__ bq, const float* __restrict__ bk,
    unsigned char* __restrict__ qk8)
{
    __shared__ __bf16 As[64 * 256];

    const int tid  = threadIdx.x;
    const int wv   = tid >> 6;
    const int lane = tid & 63;
    const int m    = lane & 15;
    const int q    = lane >> 4;
    const int mbase = blockIdx.x * 64;

    {
        const int srow = tid >> 2;
        const int c4   = tid & 3;
        int grow = mbase + srow;
        grow = grow < N_NODES ? grow : N_NODES - 1;
        const float* xp = x + (size_t)grow * DIM;
        const int mt_ = srow >> 4, m_ = srow & 15;
        #pragma unroll
        for (int i = 0; i < 16; ++i) {
            const int k = c4 * 4 + 16 * i;
            const f4v v = __builtin_nontemporal_load((const f4v*)(xp + k));
            bf4 o;
            o[0] = (__bf16)v[0]; o[1] = (__bf16)v[1];
            o[2] = (__bf16)v[2]; o[3] = (__bf16)v[3];
            const int seg = (k >> 5) * 4 + mt_;
            const int ln  = ((k >> 3) & 3) * 16 + m_;
            *(bf4*)(As + seg * 512 + ln * 8 + (k & 7)) = o;
        }
    }
    __syncthreads();

    ffrag acc[4][4] = {};

    #pragma unroll
    for (int h = 0; h < 2; ++h) {
        bfrag b[4][4];
        #pragma unroll
        for (int sp = 0; sp < 4; ++sp)
            #pragma unroll
            for (int nt = 0; nt < 4; ++nt) {
                const int col = wv * 64 + nt * 16 + m;
                b[sp][nt] = *(const bfrag*)(Wb + (size_t)col * DIM
                                            + 32 * (4 * h + sp) + 8 * q);
            }
        #pragma unroll
        for (int sp = 0; sp < 4; ++sp) {
            bfrag a[4];
            #pragma unroll
            for (int mt = 0; mt < 4; ++mt)
                a[mt] = *(const bfrag*)(As + ((4 * h + sp) * 4 + mt) * 512 + lane * 8);
            #pragma unroll
            for (int mt = 0; mt < 4; ++mt)
                #pragma unroll
                for (int nt = 0; nt < 4; ++nt)
                    acc[mt][nt] = __builtin_amdgcn_mfma_f32_16x16x32_bf16(
                                      a[mt], b[sp][nt], acc[mt][nt], 0, 0, 0);
        }
    }

    __syncthreads();
    unsigned char* ep = (unsigned char*)As;
    #pragma unroll
    for (int nt = 0; nt < 4; ++nt) {
        const int col  = wv * 64 + nt * 16 + m;
        const float bias = (col < 128) ? bq[col] : bk[col - 128];
        #pragma unroll
        for (int mt = 0; mt < 4; ++mt) {
            #pragma unroll
            for (int r = 0; r < 4; ++r) {
                const int rl = mt * 16 + q * 4 + r;
                const float v = acc[mt][nt][r] + bias;
                const int pk = __builtin_amdgcn_cvt_pk_fp8_f32(v, v, 0, false);
                ep[rl * EP_PITCH + col] = (unsigned char)(pk & 0xFF);
            }
        }
    }
    __syncthreads();
    {
        const int rl = tid >> 2;
        const int ch = tid & 3;
        const int grow = mbase + rl;
        if (grow < N_NODES) {
            const uint4* s4 = (const uint4*)(ep + rl * EP_PITCH + ch * 64);
            const uint4 t0 = s4[0], t1 = s4[1], t2 = s4[2], t3 = s4[3];
            uint4* g = (uint4*)(qk8 + (size_t)grow * QKDIM + ch * 64);
            g[0] = t0; g[1] = t1; g[2] = t2; g[3] = t3;
        }
    }
}

__global__ __launch_bounds__(256) void edge_compute(
    const unsigned char* __restrict__ qk8,
    const int* __restrict__ edge_index,
    float* __restrict__ out)
{
    const int wave = (blockIdx.x * blockDim.x + threadIdx.x) >> 6;
    const int lane = threadIdx.x & 63;
    const int g = lane >> 2;
    const int j = lane & 3;
    const int e = wave * 16 + g;

    const int src = __builtin_nontemporal_load(edge_index + e);
    const int dst = __builtin_nontemporal_load(edge_index + N_EDGES + e);

    const uint4* rs = (const uint4*)(qk8 + (size_t)src * QKDIM);
    const uint4* rd = (const uint4*)(qk8 + (size_t)dst * QKDIM);

    uint4 a[4], b[4];
    #pragma unroll
    for (int i = 0; i < 4; ++i) a[i] = rs[4 * i + j];
    #pragma unroll
    for (int i = 0; i < 4; ++i) b[i] = rd[4 * ((i + 2) & 3) + j];

    f2 acc = {0.f, 0.f};
    #pragma unroll
    for (int i = 0; i < 4; ++i) {
        const unsigned int* ua = (const unsigned int*)&a[i];
        const unsigned int* ub = (const unsigned int*)&b[i];
        #pragma unroll
        for (int t = 0; t < 4; ++t) {
            const f2 x0 = __builtin_amdgcn_cvt_pk_f32_fp8(ua[t], false);
            const f2 y0 = __builtin_amdgcn_cvt_pk_f32_fp8(ub[t], false);
            const f2 x1 = __builtin_amdgcn_cvt_pk_f32_fp8(ua[t], true);
            const f2 y1 = __builtin_amdgcn_cvt_pk_f32_fp8(ub[t], true);
            acc += x0 * y0;
            acc += x1 * y1;
        }
    }
    float p = acc[0] + acc[1];
    p += __shfl_xor(p, 1, 64);
    p += __shfl_xor(p, 2, 64);

    if (j == 0)
        out[N_NODES + e] = __expf(p * 0.0625f);
}

__global__ __launch_bounds__(1024) void phase_scatter(
    const unsigned int* __restrict__ rec, const unsigned char* __restrict__ cnts,
    float* __restrict__ out)
{
    __shared__ float acc[16][128];
    __shared__ unsigned char lc[NBLK_P];
    const int b = blockIdx.x;
    const int tid = threadIdx.x;
    const int wid = tid >> 6;
    for (int i = tid; i < 16 * 128; i += 1024) ((float*)acc)[i] = 0.f;
    if (tid < NBLK_P) lc[tid] = cnts[(size_t)tid * NB_T + b];
    __syncthreads();

    const unsigned int* rb = rec + (size_t)b * CAPB;
    for (int s = tid; s < CAPB; s += 1024) {
        const int blk = s >> 5;
        const int off = s & (SLOT - 1);
        if (off < (int)lc[blk]) {
            const unsigned int r = rb[s];
            const float v = out[N_NODES + (r & 0xFFFFF)];
            atomicAdd(&acc[wid][r >> 20], v);
        }
    }
    __syncthreads();

    if (tid < 128) {
        float s = 0.f;
        #pragma unroll
        for (int w = 0; w < 16; ++w) s += acc[w][tid];
        const int n = b * 128 + tid;
        if (n < N_NODES) out[n] = s;
    }
}

// ===================== launcher =============================================

extern "C" void kernel_launch(void* const* d_in, const int* in_sizes, int n_in,
                              void* d_out, int out_size, void* d_ws, size_t ws_size,
                              hipStream_t stream) {
    const float* x  = (const float*)d_in[0];
    const float* Wq = (const float*)d_in[1];
    const float* bq = (const float*)d_in[2];
    const float* Wk = (const float*)d_in[3];
    const float* bk = (const float*)d_in[4];
    const int* edge_index = (const int*)d_in[5];
    const int* d0 = (const int*)d_in[6] + 2 * N_EDGES;  // row 1 of d0_index
    float* out = (float*)d_out;

    char* w = (char*)d_ws;
    unsigned char* qk8 = (unsigned char*)w;  w += (size_t)N_NODES * QKDIM;   // 12.8 MB
    __bf16* Wb = (__bf16*)w;                 w += 131072;                    // 128 KB
    unsigned int* rec = (unsigned int*)w;    w += (size_t)NB_T * CAPB * 4;   // 19.6 MB (covers mega's 19.2)
    unsigned char* cnts = (unsigned char*)w; w += (size_t)NBLK_P * NB_T;     // 150 KB

    const size_t need = (size_t)(w - (char*)d_ws);
    const int ws_ok = (ws_size >= need) ? 1 : 0;

    // one-time cooperative capability + occupancy probe (accounts for the
    // kernel's REAL VGPR/LDS footprint)
    static int s_G = -2;
    if (s_G == -2) {
        int coop = 0, nsm = 0, occ = 0;
        hipDeviceGetAttribute(&coop, hipDeviceAttributeCooperativeLaunch, 0);
        hipDeviceGetAttribute(&nsm, hipDeviceAttributeMultiprocessorCount, 0);
        hipOccupancyMaxActiveBlocksPerMultiprocessor(&occ, mega, 256, 0);
        int g = (coop && occ > 0 && nsm > 0) ? occ * nsm : -1;
        if (g < NVB + 256) g = -1;   // need proj blocks + NVB bin blocks
        if (g > 2048) g = 2048;
        s_G = g;
    }

    if (ws_ok && s_G > 0) {
        void* args[] = { (void*)&x, (void*)&Wq, (void*)&Wk, (void*)&bq, (void*)&bk,
                         (void*)&edge_index, (void*)&d0, (void*)&out,
                         (void*)&qk8, (void*)&rec, (void*)&cnts };
        hipLaunchCooperativeKernel((const void*)mega, dim3(s_G), dim3(256),
                                   args, 0, stream);
    } else if (ws_ok) {
        // proven R12 4-dispatch path
        prep_bin<<<NBLK_P, 512, 0, stream>>>(Wq, Wk, Wb, d0, rec, cnts, 1);
        proj_mfma<<<(N_NODES + 63) / 64, 256, 0, stream>>>(x, Wb, bq, bk, qk8);
        edge_compute<<<N_EDGES / 64, 256, 0, stream>>>(qk8, edge_index, out);
        phase_scatter<<<NB_T, 1024, 0, stream>>>(rec, cnts, out);
    } else {
        hipMemsetAsync(out, 0, N_NODES * sizeof(float), stream);
        prep_bin<<<NBLK_P, 512, 0, stream>>>(Wq, Wk, Wb, d0, rec, cnts, 0);
        proj_mfma<<<(N_NODES + 63) / 64, 256, 0, stream>>>(x, Wb, bq, bk, qk8);
        edge_compute<<<N_EDGES / 64, 256, 0, stream>>>(qk8, edge_index, out);
        phase_scatter<<<NB_T, 1024, 0, stream>>>(rec, cnts, out);
    }
}